// Round 11
// baseline (211.871 us; speedup 1.0000x reference)
//
#include <hip/hip_runtime.h>
#include <math.h>

typedef __attribute__((ext_vector_type(8))) __bf16 bf16x8;
typedef __attribute__((ext_vector_type(8))) short short8;
typedef __attribute__((ext_vector_type(4))) float f32x4;
typedef unsigned int uint;
typedef unsigned short ushort;
typedef unsigned char uchar;

// ---------------- helpers ----------------

__device__ inline bf16x8 ld_bf8(const ushort* p){
  short8 s = *reinterpret_cast<const short8*>(p);
  return __builtin_bit_cast(bf16x8, s);
}

__device__ inline ushort f2bf(float f){
  return __builtin_bit_cast(ushort, (__bf16)f);   // native RNE cast
}
__device__ inline uint pack2bf(float a, float b){
  return (uint)f2bf(a) | ((uint)f2bf(b) << 16);
}
__device__ inline float bf_lo(uint u){ return __builtin_bit_cast(float, u << 16); }
__device__ inline float bf_hi(uint u){ return __builtin_bit_cast(float, u & 0xFFFF0000u); }

// fp8 e4m3 (OCP) pack/unpack via gfx950 native converts
template<int S>
__device__ inline float unp8(uint w){
  return __builtin_amdgcn_cvt_f32_fp8((int)w, S);
}
__device__ inline uint pk8(float a, float b, float c, float d){
  int r = 0;
  r = __builtin_amdgcn_cvt_pk_fp8_f32(a, b, r, false);   // bytes 0,1
  r = __builtin_amdgcn_cvt_pk_fp8_f32(c, d, r, true);    // bytes 2,3
  return (uint)r;
}

// ---------------- CSR build via 2-level counting sort ----------------

__global__ __launch_bounds__(256) void k_bucketA(const int* __restrict__ dst,
                                                 int* __restrict__ gbh, int E){
  __shared__ int cnt[256];
  cnt[threadIdx.x] = 0;
  __syncthreads();
  for (int e = blockIdx.x * blockDim.x + threadIdx.x; e < E; e += gridDim.x * blockDim.x)
    atomicAdd(&cnt[dst[e] >> 8], 1);
  __syncthreads();
  int c = cnt[threadIdx.x];
  if (c > 0) atomicAdd(&gbh[threadIdx.x], c);
}

__global__ __launch_bounds__(256) void k_bscan(const int* __restrict__ gbh,
                                               int* __restrict__ gbase,
                                               int* __restrict__ gcur, int NB, int E){
  __shared__ int wsum[4];
  int t = threadIdx.x;
  int c = (t < NB) ? gbh[t] : 0;
  int lane = t & 63, wv = t >> 6;
  int incl = c;
  #pragma unroll
  for (int o = 1; o < 64; o <<= 1){
    int x = __shfl_up(incl, o);
    if (lane >= o) incl += x;
  }
  if (lane == 63) wsum[wv] = incl;
  __syncthreads();
  int woff = 0;
  for (int w = 0; w < wv; ++w) woff += wsum[w];
  int excl = woff + incl - c;
  if (t < NB){ gbase[t] = excl; gcur[t] = excl; }
  if (t == 0) gbase[NB] = E;
}

#define CS_CHUNK 4096
__global__ __launch_bounds__(256) void k_bucketB(const int* __restrict__ src,
                                                 const int* __restrict__ dst,
                                                 int* __restrict__ gcur,
                                                 uint* __restrict__ epack, int E){
  __shared__ int cnt[256];
  __shared__ int wcur[256];
  const int b0 = blockIdx.x * CS_CHUNK;
  const int b1 = (b0 + CS_CHUNK < E) ? b0 + CS_CHUNK : E;
  cnt[threadIdx.x] = 0;
  __syncthreads();
  for (int e = b0 + threadIdx.x; e < b1; e += 256)
    atomicAdd(&cnt[dst[e] >> 8], 1);
  __syncthreads();
  int c = cnt[threadIdx.x];
  int base = (c > 0) ? atomicAdd(&gcur[threadIdx.x], c) : 0;
  wcur[threadIdx.x] = base;
  __syncthreads();
  for (int e = b0 + threadIdx.x; e < b1; e += 256){
    int d = dst[e];
    int s = src[e];
    int pos = atomicAdd(&wcur[d >> 8], 1);   // LDS atomic
    epack[pos] = ((uint)d << 16) | (uint)(s & 0xFFFF);
  }
}

__global__ __launch_bounds__(256) void k_bucketC(const uint* __restrict__ epack,
                                                 const int* __restrict__ gbase,
                                                 int* __restrict__ offs,
                                                 ushort* __restrict__ srclist,
                                                 int N, int E){
  __shared__ int cnt[256];
  __shared__ int wcur[256];
  __shared__ int wsum[4];
  const int b = blockIdx.x;
  const int lo = gbase[b], hi = gbase[b + 1];
  cnt[threadIdx.x] = 0;
  __syncthreads();
  for (int i = lo + threadIdx.x; i < hi; i += 256)
    atomicAdd(&cnt[(epack[i] >> 16) & 255], 1);
  __syncthreads();
  int c = cnt[threadIdx.x];
  int lane = threadIdx.x & 63, wv = threadIdx.x >> 6;
  int incl = c;
  #pragma unroll
  for (int o = 1; o < 64; o <<= 1){
    int x = __shfl_up(incl, o);
    if (lane >= o) incl += x;
  }
  if (lane == 63) wsum[wv] = incl;
  __syncthreads();
  int woff = 0;
  for (int w = 0; w < wv; ++w) woff += wsum[w];
  int excl = lo + woff + incl - c;
  int d = (b << 8) + threadIdx.x;
  if (d < N) offs[d] = excl;
  wcur[threadIdx.x] = excl;
  __syncthreads();
  for (int i = lo + threadIdx.x; i < hi; i += 256){
    uint ep = epack[i];
    int pos = atomicAdd(&wcur[(ep >> 16) & 255], 1);   // LDS atomic
    srclist[pos] = (ushort)(ep & 0xFFFF);
  }
  if (b == 0 && threadIdx.x == 0) offs[N] = E;
}

// ---------------- weight cast ----------------

struct WSet { const float* src[12]; ushort* dst[12]; int n[12]; };

__global__ __launch_bounds__(256) void k_castw(WSet ws){
  int m = blockIdx.y;
  int n = ws.n[m];
  const float* s = ws.src[m];
  ushort* d = ws.dst[m];
  for (int i = blockIdx.x * blockDim.x + threadIdx.x; i < n; i += gridDim.x * blockDim.x)
    d[i] = f2bf(s[i]);
}

// ---------------- MFMA projections: 8 waves, wave = (matrix, N-half) --------
// Per-wave weight state = bf[NT/2][KT] (<=48 VGPR) so it stays register-
// resident (the 4-wave version needed 96 VGPR of weights -> compiler reloaded
// them from global EVERY tile = 45us latency-bound kernel; VGPR_Count=92 was
// the tell). Lane holds node row = lane&15, features (half*NTW+nt)*16+kg*4.
// q/skip bf16; k/v fp8 e4m3 interleaved in kv rows (stride kvstB).

template<int KT, int NT, bool F32IN>
__global__ __launch_bounds__(512) void k_projmfma(
    const ushort* __restrict__ hin, const float* __restrict__ hinf, int N,
    const ushort* __restrict__ Wq, const ushort* __restrict__ Wk,
    const ushort* __restrict__ Wv, const ushort* __restrict__ Wsk,
    const float* __restrict__ bq, const float* __restrict__ bk,
    const float* __restrict__ bv, const float* __restrict__ bs,
    ushort* __restrict__ qo, uchar* __restrict__ kv8,
    ushort* __restrict__ so, int kvstB)
{
  constexpr int K   = KT * 32;
  constexpr int FO  = NT * 16;
  constexpr int NTW = NT / 2;          // N-tiles per wave
  const int wv6  = threadIdx.x >> 6;
  const int mat  = wv6 & 3;
  const int half = wv6 >> 2;
  const int lane = threadIdx.x & 63;
  const int r16  = lane & 15;
  const int kg   = lane >> 4;
  const int ntoff = half * NTW;

  const ushort* W = (mat == 0) ? Wq : (mat == 1) ? Wk : (mat == 2) ? Wv : Wsk;
  const float*  b = (mat == 0) ? bq : (mat == 1) ? bk : (mat == 2) ? bv : bs;

  bf16x8 bf[NTW][KT];
  #pragma unroll
  for (int nt = 0; nt < NTW; ++nt)
    #pragma unroll
    for (int kt = 0; kt < KT; ++kt)
      bf[nt][kt] = ld_bf8(W + (size_t)((ntoff + nt) * 16 + r16) * K + kt * 32 + kg * 8);

  float4 bias[NTW];
  #pragma unroll
  for (int nt = 0; nt < NTW; ++nt)
    bias[nt] = *reinterpret_cast<const float4*>(b + (ntoff + nt) * 16 + kg * 4);

  const int MT = N >> 4;
  for (int mt = blockIdx.x; mt < MT; mt += gridDim.x){
    const int row0 = mt * 16;
    bf16x8 af[KT];
    #pragma unroll
    for (int kt = 0; kt < KT; ++kt){
      if constexpr (F32IN){
        const float* xr = hinf + (size_t)(row0 + r16) * K + kt * 32 + kg * 8;
        float4 a = reinterpret_cast<const float4*>(xr)[0];
        float4 c = reinterpret_cast<const float4*>(xr)[1];
        uint4 u;
        u.x = pack2bf(a.x, a.y); u.y = pack2bf(a.z, a.w);
        u.z = pack2bf(c.x, c.y); u.w = pack2bf(c.z, c.w);
        af[kt] = __builtin_bit_cast(bf16x8, u);
      } else {
        af[kt] = ld_bf8(hin + (size_t)(row0 + r16) * K + kt * 32 + kg * 8);
      }
    }

    f32x4 acc[NTW];
    #pragma unroll
    for (int nt = 0; nt < NTW; ++nt){
      acc[nt][0] = bias[nt].x; acc[nt][1] = bias[nt].y;
      acc[nt][2] = bias[nt].z; acc[nt][3] = bias[nt].w;
    }
    #pragma unroll
    for (int nt = 0; nt < NTW; ++nt)
      #pragma unroll
      for (int kt = 0; kt < KT; ++kt)
        acc[nt] = __builtin_amdgcn_mfma_f32_16x16x32_bf16(bf[nt][kt], af[kt], acc[nt], 0, 0, 0);

    const int row = row0 + r16;
    if (mat == 0 || mat == 3){
      ushort* out = (mat == 0) ? qo : so;
      #pragma unroll
      for (int nt = 0; nt < NTW; ++nt){
        uint* p = reinterpret_cast<uint*>(out + (size_t)row * FO + (ntoff + nt) * 16 + kg * 4);
        p[0] = pack2bf(acc[nt][0], acc[nt][1]);
        p[1] = pack2bf(acc[nt][2], acc[nt][3]);
      }
    } else {
      const int voff = (mat == 2) ? FO : 0;
      #pragma unroll
      for (int nt = 0; nt < NTW; ++nt){
        uint u = pk8(acc[nt][0], acc[nt][1], acc[nt][2], acc[nt][3]);
        *reinterpret_cast<uint*>(kv8 + (size_t)row * kvstB + voff + (ntoff + nt) * 16 + kg * 4) = u;
      }
    }
  }
}

// ---------------- attention: G=8 lanes/node, fp8 kv, batched edges ----------
// 8 nodes/wave; FPL = FO/8 feats/lane. K slice = FPL fp8 bytes, V slice at
// +FO. q/skip bf16. 4 edges/batch, ping-pong prefetch (compiler-scheduled).
// MODE 0: out = bf16(relu(skip+agg)); MODE 1: out = fp32 log_softmax(skip+agg)

template<int FO, int MODE>
__global__ __launch_bounds__(256) void k_attn3(
    const ushort* __restrict__ qb, const uchar* __restrict__ kv,
    const ushort* __restrict__ skipb, const int* __restrict__ offs,
    const ushort* __restrict__ srclist, void* __restrict__ outp,
    int N, float scale)
{
  constexpr int G   = 8;
  constexpr int FPL = FO / G;        // feats per lane (12 or 4)
  constexpr int KW  = FPL / 4;       // fp8 uints per lane slice (3 or 1)
  constexpr int KVB = 2 * FO;        // bytes per kv row
  const int lane = threadIdx.x & 63;
  const int sub  = lane & 7;
  const int node = (blockIdx.x * (blockDim.x >> 6) + (threadIdx.x >> 6)) * 8 + (lane >> 3);
  const bool nv  = node < N;
  const int nodec = nv ? node : 0;

  const uint2* qrow = reinterpret_cast<const uint2*>(qb + (size_t)nodec * FO + sub * FPL);
  float qf[FPL];
  #pragma unroll
  for (int w = 0; w < KW; ++w){
    uint2 t = qrow[w];
    qf[4 * w]     = bf_lo(t.x); qf[4 * w + 1] = bf_hi(t.x);
    qf[4 * w + 2] = bf_lo(t.y); qf[4 * w + 3] = bf_hi(t.y);
  }

  float m = -INFINITY, l = 0.f;
  float acc[FPL];
  #pragma unroll
  for (int f = 0; f < FPL; ++f) acc[f] = 0.f;

  const int e0 = nv ? offs[node] : 0;
  const int e1 = nv ? offs[node + 1] : 0;

  uint kA[4][KW], vA[4][KW], kB[4][KW], vB[4][KW];

  auto DOLOAD = [&](int eb, uint (*Kr)[KW], uint (*Vr)[KW]){
    #pragma unroll
    for (int i = 0; i < 4; ++i){
      int ee = eb + i;
      int ec = (ee < e1) ? ee : (e1 - 1);
      int j = srclist[ec];
      const uchar* row = kv + (size_t)j * KVB;
      const uint* rk = reinterpret_cast<const uint*>(row + sub * FPL);
      const uint* rv = reinterpret_cast<const uint*>(row + FO + sub * FPL);
      #pragma unroll
      for (int w = 0; w < KW; ++w){
        Kr[i][w] = rk[w];
        Vr[i][w] = rv[w];
      }
    }
  };

  auto COMPUTE = [&](uint (*Kr)[KW], uint (*Vr)[KW], int ebase){
    float s[4];
    #pragma unroll
    for (int i = 0; i < 4; ++i){
      float t = 0.f;
      #pragma unroll
      for (int w = 0; w < KW; ++w){
        uint kwd = Kr[i][w];
        t = fmaf(qf[4 * w],     unp8<0>(kwd), t);
        t = fmaf(qf[4 * w + 1], unp8<1>(kwd), t);
        t = fmaf(qf[4 * w + 2], unp8<2>(kwd), t);
        t = fmaf(qf[4 * w + 3], unp8<3>(kwd), t);
      }
      s[i] = t;
    }
    #pragma unroll
    for (int o = 1; o < G; o <<= 1){
      s[0] += __shfl_xor(s[0], o);
      s[1] += __shfl_xor(s[1], o);
      s[2] += __shfl_xor(s[2], o);
      s[3] += __shfl_xor(s[3], o);
    }
    s[0] = s[0] * scale;
    s[1] = (ebase + 1 < e1) ? s[1] * scale : -1e30f;
    s[2] = (ebase + 2 < e1) ? s[2] * scale : -1e30f;
    s[3] = (ebase + 3 < e1) ? s[3] * scale : -1e30f;

    float mnew = fmaxf(fmaxf(m, s[0]), fmaxf(fmaxf(s[1], s[2]), s[3]));
    float sfac = __expf(m - mnew);
    float p4[4];
    p4[0] = __expf(s[0] - mnew);
    p4[1] = __expf(s[1] - mnew);
    p4[2] = __expf(s[2] - mnew);
    p4[3] = __expf(s[3] - mnew);
    l = l * sfac + (p4[0] + p4[1]) + (p4[2] + p4[3]);
    #pragma unroll
    for (int f = 0; f < FPL; ++f) acc[f] *= sfac;
    #pragma unroll
    for (int i = 0; i < 4; ++i){
      #pragma unroll
      for (int w = 0; w < KW; ++w){
        uint vwd = Vr[i][w];
        acc[4 * w]     = fmaf(p4[i], unp8<0>(vwd), acc[4 * w]);
        acc[4 * w + 1] = fmaf(p4[i], unp8<1>(vwd), acc[4 * w + 1]);
        acc[4 * w + 2] = fmaf(p4[i], unp8<2>(vwd), acc[4 * w + 2]);
        acc[4 * w + 3] = fmaf(p4[i], unp8<3>(vwd), acc[4 * w + 3]);
      }
    }
    m = mnew;
  };

  if (e0 < e1){
    int e = e0;
    DOLOAD(e, kA, vA);
    for (;;){
      int en = e + 4;
      bool more = en < e1;
      if (more) DOLOAD(en, kB, vB);
      COMPUTE(kA, vA, e);
      e = en;
      if (!more) break;
      en = e + 4;
      more = en < e1;
      if (more) DOLOAD(en, kA, vA);
      COMPUTE(kB, vB, e);
      e = en;
      if (!more) break;
    }
  }

  float inv = 1.f / fmaxf(l, 1e-16f);
  const uint2* srow = reinterpret_cast<const uint2*>(skipb + (size_t)nodec * FO + sub * FPL);
  float val[FPL];
  #pragma unroll
  for (int w = 0; w < KW; ++w){
    uint2 t = srow[w];
    val[4 * w]     = bf_lo(t.x) + acc[4 * w] * inv;
    val[4 * w + 1] = bf_hi(t.x) + acc[4 * w + 1] * inv;
    val[4 * w + 2] = bf_lo(t.y) + acc[4 * w + 2] * inv;
    val[4 * w + 3] = bf_hi(t.y) + acc[4 * w + 3] * inv;
  }

  if (MODE == 0){
    if (nv){
      uint2* orow = reinterpret_cast<uint2*>((ushort*)outp + (size_t)node * FO + sub * FPL);
      #pragma unroll
      for (int w = 0; w < KW; ++w){
        uint2 o;
        o.x = pack2bf(fmaxf(val[4 * w], 0.f),     fmaxf(val[4 * w + 1], 0.f));
        o.y = pack2bf(fmaxf(val[4 * w + 2], 0.f), fmaxf(val[4 * w + 3], 0.f));
        orow[w] = o;
      }
    }
  } else {
    float mx = -INFINITY;
    #pragma unroll
    for (int f = 0; f < FPL; ++f) mx = fmaxf(mx, val[f]);
    #pragma unroll
    for (int o = 1; o < G; o <<= 1) mx = fmaxf(mx, __shfl_xor(mx, o));
    float ssum = 0.f;
    #pragma unroll
    for (int f = 0; f < FPL; ++f) ssum += __expf(val[f] - mx);
    #pragma unroll
    for (int o = 1; o < G; o <<= 1) ssum += __shfl_xor(ssum, o);
    float lg = __logf(ssum);
    if (nv){
      float* orow = (float*)outp + (size_t)node * FO + sub * FPL;
      #pragma unroll
      for (int f = 0; f < FPL; ++f) orow[f] = val[f] - mx - lg;
    }
  }
}

// ---------------- launch ----------------

extern "C" void kernel_launch(void* const* d_in, const int* in_sizes, int n_in,
                              void* d_out, int out_size, void* d_ws, size_t ws_size,
                              hipStream_t stream)
{
  const float* x  = (const float*)d_in[0];
  const int*   ei = (const int*)d_in[1];
  const int N = in_sizes[0] / 128;
  const int E = in_sizes[1] / 2;

  const float* W1[4]; const float* b1[4];
  const float* W2[4]; const float* b2[4];
  const float* W3[4]; const float* b3[4];
  for (int i = 0; i < 4; ++i){
    W1[i] = (const float*)d_in[2 + i];   b1[i] = (const float*)d_in[6 + i];
    W2[i] = (const float*)d_in[10 + i];  b2[i] = (const float*)d_in[14 + i];
    W3[i] = (const float*)d_in[18 + i];  b3[i] = (const float*)d_in[22 + i];
  }

  size_t off = 0;
  auto alloc = [&](size_t bytes) -> void* {
    void* p = (char*)d_ws + off;
    off = (off + bytes + 255) & ~(size_t)255;
    return p;
  };
  const int NB = (N + 255) / 256;
  int* offs       = (int*)alloc(((size_t)N + 1) * 4);
  int* gbh        = (int*)alloc(256 * 4);
  int* gbase      = (int*)alloc(260 * 4);
  int* gcur       = (int*)alloc(256 * 4);
  uint* epack     = (uint*)alloc((size_t)E * 4);
  ushort* srclist = (ushort*)alloc((size_t)E * 2);
  ushort* qb  = (ushort*)alloc((size_t)N * 96 * 2);
  uchar*  kvb = (uchar*)alloc((size_t)N * 192);
  ushort* sb  = (ushort*)alloc((size_t)N * 96 * 2);
  ushort* hb  = (ushort*)alloc((size_t)N * 128 * 2);
  ushort* wb  = (ushort*)alloc((size_t)98304 * 2);

  ushort* Wb1[4]; ushort* Wb2[4]; ushort* Wb3[4];
  for (int i = 0; i < 4; ++i){
    Wb1[i] = wb + (size_t)i * 12288;
    Wb2[i] = wb + 49152 + (size_t)i * 9216;
    Wb3[i] = wb + 49152 + 36864 + (size_t)i * 3072;
  }

  WSet wset;
  for (int i = 0; i < 4; ++i){
    wset.src[i]     = W1[i]; wset.dst[i]     = Wb1[i]; wset.n[i]     = 12288;
    wset.src[4 + i] = W2[i]; wset.dst[4 + i] = Wb2[i]; wset.n[4 + i] = 9216;
    wset.src[8 + i] = W3[i]; wset.dst[8 + i] = Wb3[i]; wset.n[8 + i] = 3072;
  }
  k_castw<<<dim3(48, 12), dim3(256), 0, stream>>>(wset);

  // --- CSR of incoming edges (2-level counting sort) ---
  const int* esrc = ei;
  const int* edst = ei + E;
  hipMemsetAsync(gbh, 0, 256 * 4, stream);
  k_bucketA<<<dim3(392), dim3(256), 0, stream>>>(edst, gbh, E);
  k_bscan<<<dim3(1), dim3(256), 0, stream>>>(gbh, gbase, gcur, NB, E);
  const int nCB = (E + CS_CHUNK - 1) / CS_CHUNK;
  k_bucketB<<<dim3(nCB), dim3(256), 0, stream>>>(esrc, edst, gcur, epack, E);
  k_bucketC<<<dim3(NB), dim3(256), 0, stream>>>(epack, gbase, offs, srclist, N, E);

  float* outf = (float*)d_out;
  const float sc96 = 1.0f / sqrtf(96.f);
  const float sc32 = 1.0f / sqrtf(32.f);

  const int MT = N / 16;
  const int tpb = (MT + 1023) / 1024;
  const int gridP = (MT + tpb - 1) / tpb;
  const int gridA = (N + 31) / 32;

  // layer 1: K=128, FO=96 (fp32 x in, cast fused)
  k_projmfma<4, 6, true><<<dim3(gridP), dim3(512), 0, stream>>>(nullptr, x, N,
      Wb1[0], Wb1[1], Wb1[2], Wb1[3], b1[0], b1[1], b1[2], b1[3],
      qb, kvb, sb, 192);
  k_attn3<96, 0><<<dim3(gridA), dim3(256), 0, stream>>>(qb, kvb, sb, offs, srclist, hb, N, sc96);

  // layer 2: K=96, FO=96
  k_projmfma<3, 6, false><<<dim3(gridP), dim3(512), 0, stream>>>(hb, nullptr, N,
      Wb2[0], Wb2[1], Wb2[2], Wb2[3], b2[0], b2[1], b2[2], b2[3],
      qb, kvb, sb, 192);
  k_attn3<96, 0><<<dim3(gridA), dim3(256), 0, stream>>>(qb, kvb, sb, offs, srclist, hb, N, sc96);

  // layer 3: K=96, FO=32 (+ fused log_softmax)
  k_projmfma<3, 2, false><<<dim3(gridP), dim3(512), 0, stream>>>(hb, nullptr, N,
      Wb3[0], Wb3[1], Wb3[2], Wb3[3], b3[0], b3[1], b3[2], b3[3],
      qb, kvb, sb, 64);
  k_attn3<32, 1><<<dim3(gridA), dim3(256), 0, stream>>>(qb, kvb, sb, offs, srclist, outf, N, sc32);
}

// Round 12
// 186.043 us; speedup vs baseline: 1.1388x; 1.1388x over previous
//
#include <hip/hip_runtime.h>
#include <math.h>

typedef __attribute__((ext_vector_type(8))) __bf16 bf16x8;
typedef __attribute__((ext_vector_type(8))) short short8;
typedef __attribute__((ext_vector_type(4))) float f32x4;
typedef unsigned int uint;
typedef unsigned short ushort;
typedef unsigned char uchar;

// ---------------- helpers ----------------

__device__ inline bf16x8 ld_bf8(const ushort* p){
  short8 s = *reinterpret_cast<const short8*>(p);
  return __builtin_bit_cast(bf16x8, s);
}

__device__ inline ushort f2bf(float f){
  return __builtin_bit_cast(ushort, (__bf16)f);   // native RNE cast
}
__device__ inline uint pack2bf(float a, float b){
  return (uint)f2bf(a) | ((uint)f2bf(b) << 16);
}
__device__ inline float bf_lo(uint u){ return __builtin_bit_cast(float, u << 16); }
__device__ inline float bf_hi(uint u){ return __builtin_bit_cast(float, u & 0xFFFF0000u); }

// fp8 e4m3 (OCP) pack/unpack via gfx950 native converts
template<int S>
__device__ inline float unp8(uint w){
  return __builtin_amdgcn_cvt_f32_fp8((int)w, S);
}
__device__ inline uint pk8(float a, float b, float c, float d){
  int r = 0;
  r = __builtin_amdgcn_cvt_pk_fp8_f32(a, b, r, false);   // bytes 0,1
  r = __builtin_amdgcn_cvt_pk_fp8_f32(c, d, r, true);    // bytes 2,3
  return (uint)r;
}

// ---------------- CSR build via 2-level counting sort ----------------

__global__ void k_zero(int* __restrict__ p, int n){
  if ((int)threadIdx.x < n) p[threadIdx.x] = 0;
}

__global__ __launch_bounds__(256) void k_bucketA(const int* __restrict__ dst,
                                                 int* __restrict__ gbh, int E){
  __shared__ int cnt[256];
  cnt[threadIdx.x] = 0;
  __syncthreads();
  for (int e = blockIdx.x * blockDim.x + threadIdx.x; e < E; e += gridDim.x * blockDim.x)
    atomicAdd(&cnt[dst[e] >> 8], 1);
  __syncthreads();
  int c = cnt[threadIdx.x];
  if (c > 0) atomicAdd(&gbh[threadIdx.x], c);
}

__global__ __launch_bounds__(256) void k_bscan(const int* __restrict__ gbh,
                                               int* __restrict__ gbase,
                                               int* __restrict__ gcur, int NB, int E){
  __shared__ int wsum[4];
  int t = threadIdx.x;
  int c = (t < NB) ? gbh[t] : 0;
  int lane = t & 63, wv = t >> 6;
  int incl = c;
  #pragma unroll
  for (int o = 1; o < 64; o <<= 1){
    int x = __shfl_up(incl, o);
    if (lane >= o) incl += x;
  }
  if (lane == 63) wsum[wv] = incl;
  __syncthreads();
  int woff = 0;
  for (int w = 0; w < wv; ++w) woff += wsum[w];
  int excl = woff + incl - c;
  if (t < NB){ gbase[t] = excl; gcur[t] = excl; }
  if (t == 0) gbase[NB] = E;
}

#define CS_CHUNK 4096
__global__ __launch_bounds__(256) void k_bucketB(const int* __restrict__ src,
                                                 const int* __restrict__ dst,
                                                 int* __restrict__ gcur,
                                                 uint* __restrict__ epack, int E){
  __shared__ int cnt[256];
  __shared__ int wcur[256];
  const int b0 = blockIdx.x * CS_CHUNK;
  const int b1 = (b0 + CS_CHUNK < E) ? b0 + CS_CHUNK : E;
  cnt[threadIdx.x] = 0;
  __syncthreads();
  for (int e = b0 + threadIdx.x; e < b1; e += 256)
    atomicAdd(&cnt[dst[e] >> 8], 1);
  __syncthreads();
  int c = cnt[threadIdx.x];
  int base = (c > 0) ? atomicAdd(&gcur[threadIdx.x], c) : 0;
  wcur[threadIdx.x] = base;
  __syncthreads();
  for (int e = b0 + threadIdx.x; e < b1; e += 256){
    int d = dst[e];
    int s = src[e];
    int pos = atomicAdd(&wcur[d >> 8], 1);   // LDS atomic
    epack[pos] = ((uint)d << 16) | (uint)(s & 0xFFFF);
  }
}

__global__ __launch_bounds__(256) void k_bucketC(const uint* __restrict__ epack,
                                                 const int* __restrict__ gbase,
                                                 int* __restrict__ offs,
                                                 ushort* __restrict__ srclist,
                                                 int N, int E){
  __shared__ int cnt[256];
  __shared__ int wcur[256];
  __shared__ int wsum[4];
  const int b = blockIdx.x;
  const int lo = gbase[b], hi = gbase[b + 1];
  cnt[threadIdx.x] = 0;
  __syncthreads();
  for (int i = lo + threadIdx.x; i < hi; i += 256)
    atomicAdd(&cnt[(epack[i] >> 16) & 255], 1);
  __syncthreads();
  int c = cnt[threadIdx.x];
  int lane = threadIdx.x & 63, wv = threadIdx.x >> 6;
  int incl = c;
  #pragma unroll
  for (int o = 1; o < 64; o <<= 1){
    int x = __shfl_up(incl, o);
    if (lane >= o) incl += x;
  }
  if (lane == 63) wsum[wv] = incl;
  __syncthreads();
  int woff = 0;
  for (int w = 0; w < wv; ++w) woff += wsum[w];
  int excl = lo + woff + incl - c;
  int d = (b << 8) + threadIdx.x;
  if (d < N) offs[d] = excl;
  wcur[threadIdx.x] = excl;
  __syncthreads();
  for (int i = lo + threadIdx.x; i < hi; i += 256){
    uint ep = epack[i];
    int pos = atomicAdd(&wcur[(ep >> 16) & 255], 1);   // LDS atomic
    srclist[pos] = (ushort)(ep & 0xFFFF);
  }
  if (b == 0 && threadIdx.x == 0) offs[N] = E;
}

// ---------------- weight cast ----------------

struct WSet { const float* src[12]; ushort* dst[12]; int n[12]; };

__global__ __launch_bounds__(256) void k_castw(WSet ws){
  int m = blockIdx.y;
  int n = ws.n[m];
  const float* s = ws.src[m];
  ushort* d = ws.dst[m];
  for (int i = blockIdx.x * blockDim.x + threadIdx.x; i < n; i += gridDim.x * blockDim.x)
    d[i] = f2bf(s[i]);
}

// ---------------- MFMA projections: weights in LDS ----------------
// blockIdx.y = matrix (0=q,1=k,2=v,3=skip); 4 waves/block all on that matrix,
// each wave owns a different 16-row tile (stride gridDim.x*4). W staged once
// into LDS with padded row stride PS=K+8 halves (272B/208B -> lane bank
// offsets cover all 32 banks, 2-way aliasing = free). Per tile: NT*KT
// ds_read_b128 + NT*KT mfma — no dependence on register-residency heuristics
// (r10/r11 failure: compiler sank 96/48-VGPR weight arrays back to global
// reloads inside the loop; VGPR_Count 92/56 was the tell).
// q/skip stored bf16; k/v fp8 e4m3 interleaved in kv rows (stride kvstB).

template<int KT, int NT, bool F32IN>
__global__ __launch_bounds__(256) void k_projmfma(
    const ushort* __restrict__ hin, const float* __restrict__ hinf, int N,
    const ushort* __restrict__ Wq, const ushort* __restrict__ Wk,
    const ushort* __restrict__ Wv, const ushort* __restrict__ Wsk,
    const float* __restrict__ bq, const float* __restrict__ bk,
    const float* __restrict__ bv, const float* __restrict__ bs,
    ushort* __restrict__ qo, uchar* __restrict__ kv8,
    ushort* __restrict__ so, int kvstB)
{
  constexpr int K  = KT * 32;
  constexpr int PS = K + 8;            // padded LDS row stride (halves)
  constexpr int FO = NT * 16;
  __shared__ ushort wlds[FO * PS];

  const int mat = blockIdx.y;
  const ushort* W = (mat == 0) ? Wq : (mat == 1) ? Wk : (mat == 2) ? Wv : Wsk;
  const float*  b = (mat == 0) ? bq : (mat == 1) ? bk : (mat == 2) ? bv : bs;

  // stage W -> LDS (row-major, padded stride)
  for (int idx = threadIdx.x; idx < FO * (K / 8); idx += 256){
    int row = idx / (K / 8);
    int c8  = idx - row * (K / 8);
    *reinterpret_cast<short8*>(&wlds[row * PS + c8 * 8]) =
        *reinterpret_cast<const short8*>(W + (size_t)row * K + c8 * 8);
  }
  __syncthreads();

  const int wv   = threadIdx.x >> 6;
  const int lane = threadIdx.x & 63;
  const int r16  = lane & 15;
  const int kg   = lane >> 4;

  float4 bias[NT];
  #pragma unroll
  for (int nt = 0; nt < NT; ++nt)
    bias[nt] = *reinterpret_cast<const float4*>(b + nt * 16 + kg * 4);

  const int MT = N >> 4;
  for (int mt = blockIdx.x * 4 + wv; mt < MT; mt += gridDim.x * 4){
    const int row0 = mt * 16;
    bf16x8 af[KT];
    #pragma unroll
    for (int kt = 0; kt < KT; ++kt){
      if constexpr (F32IN){
        const float* xr = hinf + (size_t)(row0 + r16) * K + kt * 32 + kg * 8;
        float4 a = reinterpret_cast<const float4*>(xr)[0];
        float4 c = reinterpret_cast<const float4*>(xr)[1];
        uint4 u;
        u.x = pack2bf(a.x, a.y); u.y = pack2bf(a.z, a.w);
        u.z = pack2bf(c.x, c.y); u.w = pack2bf(c.z, c.w);
        af[kt] = __builtin_bit_cast(bf16x8, u);
      } else {
        af[kt] = ld_bf8(hin + (size_t)(row0 + r16) * K + kt * 32 + kg * 8);
      }
    }

    f32x4 acc[NT];
    #pragma unroll
    for (int nt = 0; nt < NT; ++nt){
      acc[nt][0] = bias[nt].x; acc[nt][1] = bias[nt].y;
      acc[nt][2] = bias[nt].z; acc[nt][3] = bias[nt].w;
    }
    #pragma unroll
    for (int nt = 0; nt < NT; ++nt)
      #pragma unroll
      for (int kt = 0; kt < KT; ++kt){
        bf16x8 bfr = ld_bf8(&wlds[(nt * 16 + r16) * PS + kt * 32 + kg * 8]);
        acc[nt] = __builtin_amdgcn_mfma_f32_16x16x32_bf16(bfr, af[kt], acc[nt], 0, 0, 0);
      }

    const int row = row0 + r16;
    if (mat == 0 || mat == 3){
      ushort* out = (mat == 0) ? qo : so;
      #pragma unroll
      for (int nt = 0; nt < NT; ++nt){
        uint* p = reinterpret_cast<uint*>(out + (size_t)row * FO + nt * 16 + kg * 4);
        p[0] = pack2bf(acc[nt][0], acc[nt][1]);
        p[1] = pack2bf(acc[nt][2], acc[nt][3]);
      }
    } else {
      const int voff = (mat == 2) ? FO : 0;
      #pragma unroll
      for (int nt = 0; nt < NT; ++nt){
        uint u = pk8(acc[nt][0], acc[nt][1], acc[nt][2], acc[nt][3]);
        *reinterpret_cast<uint*>(kv8 + (size_t)row * kvstB + voff + nt * 16 + kg * 4) = u;
      }
    }
  }
}

// ---------------- attention: G=8 lanes/node, fp8 kv, batched edges ----------
// 8 nodes/wave; FPL = FO/8 feats/lane. K slice = FPL fp8 bytes, V slice at
// +FO. q/skip bf16. 4 edges/batch, ping-pong prefetch (compiler-scheduled).
// MODE 0: out = bf16(relu(skip+agg)); MODE 1: out = fp32 log_softmax(skip+agg)

template<int FO, int MODE>
__global__ __launch_bounds__(256) void k_attn3(
    const ushort* __restrict__ qb, const uchar* __restrict__ kv,
    const ushort* __restrict__ skipb, const int* __restrict__ offs,
    const ushort* __restrict__ srclist, void* __restrict__ outp,
    int N, float scale)
{
  constexpr int G   = 8;
  constexpr int FPL = FO / G;        // feats per lane (12 or 4)
  constexpr int KW  = FPL / 4;       // fp8 uints per lane slice (3 or 1)
  constexpr int KVB = 2 * FO;        // bytes per kv row
  const int lane = threadIdx.x & 63;
  const int sub  = lane & 7;
  const int node = (blockIdx.x * (blockDim.x >> 6) + (threadIdx.x >> 6)) * 8 + (lane >> 3);
  const bool nv  = node < N;
  const int nodec = nv ? node : 0;

  const uint2* qrow = reinterpret_cast<const uint2*>(qb + (size_t)nodec * FO + sub * FPL);
  float qf[FPL];
  #pragma unroll
  for (int w = 0; w < KW; ++w){
    uint2 t = qrow[w];
    qf[4 * w]     = bf_lo(t.x); qf[4 * w + 1] = bf_hi(t.x);
    qf[4 * w + 2] = bf_lo(t.y); qf[4 * w + 3] = bf_hi(t.y);
  }

  float m = -INFINITY, l = 0.f;
  float acc[FPL];
  #pragma unroll
  for (int f = 0; f < FPL; ++f) acc[f] = 0.f;

  const int e0 = nv ? offs[node] : 0;
  const int e1 = nv ? offs[node + 1] : 0;

  uint kA[4][KW], vA[4][KW], kB[4][KW], vB[4][KW];

  auto DOLOAD = [&](int eb, uint (*Kr)[KW], uint (*Vr)[KW]){
    #pragma unroll
    for (int i = 0; i < 4; ++i){
      int ee = eb + i;
      int ec = (ee < e1) ? ee : (e1 - 1);
      int j = srclist[ec];
      const uchar* row = kv + (size_t)j * KVB;
      const uint* rk = reinterpret_cast<const uint*>(row + sub * FPL);
      const uint* rv = reinterpret_cast<const uint*>(row + FO + sub * FPL);
      #pragma unroll
      for (int w = 0; w < KW; ++w){
        Kr[i][w] = rk[w];
        Vr[i][w] = rv[w];
      }
    }
  };

  auto COMPUTE = [&](uint (*Kr)[KW], uint (*Vr)[KW], int ebase){
    float s[4];
    #pragma unroll
    for (int i = 0; i < 4; ++i){
      float t = 0.f;
      #pragma unroll
      for (int w = 0; w < KW; ++w){
        uint kwd = Kr[i][w];
        t = fmaf(qf[4 * w],     unp8<0>(kwd), t);
        t = fmaf(qf[4 * w + 1], unp8<1>(kwd), t);
        t = fmaf(qf[4 * w + 2], unp8<2>(kwd), t);
        t = fmaf(qf[4 * w + 3], unp8<3>(kwd), t);
      }
      s[i] = t;
    }
    #pragma unroll
    for (int o = 1; o < G; o <<= 1){
      s[0] += __shfl_xor(s[0], o);
      s[1] += __shfl_xor(s[1], o);
      s[2] += __shfl_xor(s[2], o);
      s[3] += __shfl_xor(s[3], o);
    }
    s[0] = s[0] * scale;
    s[1] = (ebase + 1 < e1) ? s[1] * scale : -1e30f;
    s[2] = (ebase + 2 < e1) ? s[2] * scale : -1e30f;
    s[3] = (ebase + 3 < e1) ? s[3] * scale : -1e30f;

    float mnew = fmaxf(fmaxf(m, s[0]), fmaxf(fmaxf(s[1], s[2]), s[3]));
    float sfac = __expf(m - mnew);
    float p4[4];
    p4[0] = __expf(s[0] - mnew);
    p4[1] = __expf(s[1] - mnew);
    p4[2] = __expf(s[2] - mnew);
    p4[3] = __expf(s[3] - mnew);
    l = l * sfac + (p4[0] + p4[1]) + (p4[2] + p4[3]);
    #pragma unroll
    for (int f = 0; f < FPL; ++f) acc[f] *= sfac;
    #pragma unroll
    for (int i = 0; i < 4; ++i){
      #pragma unroll
      for (int w = 0; w < KW; ++w){
        uint vwd = Vr[i][w];
        acc[4 * w]     = fmaf(p4[i], unp8<0>(vwd), acc[4 * w]);
        acc[4 * w + 1] = fmaf(p4[i], unp8<1>(vwd), acc[4 * w + 1]);
        acc[4 * w + 2] = fmaf(p4[i], unp8<2>(vwd), acc[4 * w + 2]);
        acc[4 * w + 3] = fmaf(p4[i], unp8<3>(vwd), acc[4 * w + 3]);
      }
    }
    m = mnew;
  };

  if (e0 < e1){
    int e = e0;
    DOLOAD(e, kA, vA);
    for (;;){
      int en = e + 4;
      bool more = en < e1;
      if (more) DOLOAD(en, kB, vB);
      COMPUTE(kA, vA, e);
      e = en;
      if (!more) break;
      en = e + 4;
      more = en < e1;
      if (more) DOLOAD(en, kA, vA);
      COMPUTE(kB, vB, e);
      e = en;
      if (!more) break;
    }
  }

  float inv = 1.f / fmaxf(l, 1e-16f);
  const uint2* srow = reinterpret_cast<const uint2*>(skipb + (size_t)nodec * FO + sub * FPL);
  float val[FPL];
  #pragma unroll
  for (int w = 0; w < KW; ++w){
    uint2 t = srow[w];
    val[4 * w]     = bf_lo(t.x) + acc[4 * w] * inv;
    val[4 * w + 1] = bf_hi(t.x) + acc[4 * w + 1] * inv;
    val[4 * w + 2] = bf_lo(t.y) + acc[4 * w + 2] * inv;
    val[4 * w + 3] = bf_hi(t.y) + acc[4 * w + 3] * inv;
  }

  if (MODE == 0){
    if (nv){
      uint2* orow = reinterpret_cast<uint2*>((ushort*)outp + (size_t)node * FO + sub * FPL);
      #pragma unroll
      for (int w = 0; w < KW; ++w){
        uint2 o;
        o.x = pack2bf(fmaxf(val[4 * w], 0.f),     fmaxf(val[4 * w + 1], 0.f));
        o.y = pack2bf(fmaxf(val[4 * w + 2], 0.f), fmaxf(val[4 * w + 3], 0.f));
        orow[w] = o;
      }
    }
  } else {
    float mx = -INFINITY;
    #pragma unroll
    for (int f = 0; f < FPL; ++f) mx = fmaxf(mx, val[f]);
    #pragma unroll
    for (int o = 1; o < G; o <<= 1) mx = fmaxf(mx, __shfl_xor(mx, o));
    float ssum = 0.f;
    #pragma unroll
    for (int f = 0; f < FPL; ++f) ssum += __expf(val[f] - mx);
    #pragma unroll
    for (int o = 1; o < G; o <<= 1) ssum += __shfl_xor(ssum, o);
    float lg = __logf(ssum);
    if (nv){
      float* orow = (float*)outp + (size_t)node * FO + sub * FPL;
      #pragma unroll
      for (int f = 0; f < FPL; ++f) orow[f] = val[f] - mx - lg;
    }
  }
}

// ---------------- launch ----------------

extern "C" void kernel_launch(void* const* d_in, const int* in_sizes, int n_in,
                              void* d_out, int out_size, void* d_ws, size_t ws_size,
                              hipStream_t stream)
{
  const float* x  = (const float*)d_in[0];
  const int*   ei = (const int*)d_in[1];
  const int N = in_sizes[0] / 128;
  const int E = in_sizes[1] / 2;

  const float* W1[4]; const float* b1[4];
  const float* W2[4]; const float* b2[4];
  const float* W3[4]; const float* b3[4];
  for (int i = 0; i < 4; ++i){
    W1[i] = (const float*)d_in[2 + i];   b1[i] = (const float*)d_in[6 + i];
    W2[i] = (const float*)d_in[10 + i];  b2[i] = (const float*)d_in[14 + i];
    W3[i] = (const float*)d_in[18 + i];  b3[i] = (const float*)d_in[22 + i];
  }

  size_t off = 0;
  auto alloc = [&](size_t bytes) -> void* {
    void* p = (char*)d_ws + off;
    off = (off + bytes + 255) & ~(size_t)255;
    return p;
  };
  const int NB = (N + 255) / 256;
  int* offs       = (int*)alloc(((size_t)N + 1) * 4);
  int* gbh        = (int*)alloc(256 * 4);
  int* gbase      = (int*)alloc(260 * 4);
  int* gcur       = (int*)alloc(256 * 4);
  uint* epack     = (uint*)alloc((size_t)E * 4);
  ushort* srclist = (ushort*)alloc((size_t)E * 2);
  ushort* qb  = (ushort*)alloc((size_t)N * 96 * 2);
  uchar*  kvb = (uchar*)alloc((size_t)N * 192);
  ushort* sb  = (ushort*)alloc((size_t)N * 96 * 2);
  ushort* hb  = (ushort*)alloc((size_t)N * 128 * 2);
  ushort* wb  = (ushort*)alloc((size_t)98304 * 2);

  ushort* Wb1[4]; ushort* Wb2[4]; ushort* Wb3[4];
  for (int i = 0; i < 4; ++i){
    Wb1[i] = wb + (size_t)i * 12288;
    Wb2[i] = wb + 49152 + (size_t)i * 9216;
    Wb3[i] = wb + 49152 + 36864 + (size_t)i * 3072;
  }

  WSet wset;
  for (int i = 0; i < 4; ++i){
    wset.src[i]     = W1[i]; wset.dst[i]     = Wb1[i]; wset.n[i]     = 12288;
    wset.src[4 + i] = W2[i]; wset.dst[4 + i] = Wb2[i]; wset.n[4 + i] = 9216;
    wset.src[8 + i] = W3[i]; wset.dst[8 + i] = Wb3[i]; wset.n[8 + i] = 3072;
  }
  k_castw<<<dim3(48, 12), dim3(256), 0, stream>>>(wset);

  // --- CSR of incoming edges (2-level counting sort) ---
  const int* esrc = ei;
  const int* edst = ei + E;
  k_zero<<<dim3(1), dim3(256), 0, stream>>>(gbh, 256);
  k_bucketA<<<dim3(392), dim3(256), 0, stream>>>(edst, gbh, E);
  k_bscan<<<dim3(1), dim3(256), 0, stream>>>(gbh, gbase, gcur, NB, E);
  const int nCB = (E + CS_CHUNK - 1) / CS_CHUNK;
  k_bucketB<<<dim3(nCB), dim3(256), 0, stream>>>(esrc, edst, gcur, epack, E);
  k_bucketC<<<dim3(NB), dim3(256), 0, stream>>>(epack, gbase, offs, srclist, N, E);

  float* outf = (float*)d_out;
  const float sc96 = 1.0f / sqrtf(96.f);
  const float sc32 = 1.0f / sqrtf(32.f);

  const int gridA = (N + 31) / 32;

  // layer 1: K=128, FO=96 (fp32 x in, cast fused)
  k_projmfma<4, 6, true><<<dim3(384, 4), dim3(256), 0, stream>>>(nullptr, x, N,
      Wb1[0], Wb1[1], Wb1[2], Wb1[3], b1[0], b1[1], b1[2], b1[3],
      qb, kvb, sb, 192);
  k_attn3<96, 0><<<dim3(gridA), dim3(256), 0, stream>>>(qb, kvb, sb, offs, srclist, hb, N, sc96);

  // layer 2: K=96, FO=96
  k_projmfma<3, 6, false><<<dim3(384, 4), dim3(256), 0, stream>>>(hb, nullptr, N,
      Wb2[0], Wb2[1], Wb2[2], Wb2[3], b2[0], b2[1], b2[2], b2[3],
      qb, kvb, sb, 192);
  k_attn3<96, 0><<<dim3(gridA), dim3(256), 0, stream>>>(qb, kvb, sb, offs, srclist, hb, N, sc96);

  // layer 3: K=96, FO=32 (+ fused log_softmax)
  k_projmfma<3, 2, false><<<dim3(384, 4), dim3(256), 0, stream>>>(hb, nullptr, N,
      Wb3[0], Wb3[1], Wb3[2], Wb3[3], b3[0], b3[1], b3[2], b3[3],
      qb, kvb, sb, 64);
  k_attn3<32, 1><<<dim3(gridA), dim3(256), 0, stream>>>(qb, kvb, sb, offs, srclist, outf, N, sc32);
}